// Round 14
// baseline (170.014 us; speedup 1.0000x reference)
//
#include <hip/hip_runtime.h>
#include <cstdint>

typedef __attribute__((ext_vector_type(8))) short short8;
typedef __attribute__((ext_vector_type(4))) float f32x4;

static __device__ __forceinline__ unsigned short f2bf(float x) {
  union { float f; unsigned int u; } c; c.f = x;
  unsigned int u = c.u;
  unsigned int r = (u + 0x7fffu + ((u >> 16) & 1u)) >> 16;  // RNE
  return (unsigned short)r;
}

static __device__ __forceinline__ unsigned int cvt_pk_bf16(float a, float b) {
  unsigned int r;
  asm("v_cvt_pk_bf16_f32 %0, %1, %2" : "=v"(r) : "v"(a), "v"(b));
  return r;
}

static __device__ __forceinline__ uint2 shfl64(uint2 v, int lane) {
  uint2 r;
  r.x = (unsigned int)__shfl((int)v.x, lane);
  r.y = (unsigned int)__shfl((int)v.y, lane);
  return r;
}

static __device__ __forceinline__ void gl_lds16(const void* g, void* l) {
  __builtin_amdgcn_global_load_lds((const __attribute__((address_space(1))) void*)g,
                                   (__attribute__((address_space(3))) void*)l, 16, 0, 0);
}

// ---------- fused prep: weight transposes + hidden f32->bf16 + sincos table ----------
__global__ __launch_bounds__(256) void k_prep(const float* __restrict__ wq,
                                              const float* __restrict__ wk,
                                              const float* __restrict__ wv,
                                              const float* __restrict__ wo,
                                              const float* __restrict__ hs,
                                              unsigned short* __restrict__ wqt,
                                              unsigned short* __restrict__ wkt,
                                              unsigned short* __restrict__ wvt,
                                              unsigned short* __restrict__ wot,
                                              unsigned short* __restrict__ hb,
                                              float2* __restrict__ ctab) {
  int id = blockIdx.x;
  if (id >= 10240) {
    if (id < 14336) {          // hidden f32 -> bf16 (float4 per thread)
      int i = (id - 10240) * 256 + threadIdx.x;
      float4 v = reinterpret_cast<const float4*>(hs)[i];
      ushort4 o;
      o.x = f2bf(v.x); o.y = f2bf(v.y); o.z = f2bf(v.z); o.w = f2bf(v.w);
      reinterpret_cast<ushort4*>(hb)[i] = o;
    } else {                   // sincos table (2048*64)
      int idx = (id - 14336) * 256 + threadIdx.x;
      int s = idx >> 6, i = idx & 63;
      float freq = powf(10000.0f, -(float)i / 64.0f);
      float sn, cs;
      sincosf((float)s * freq, &sn, &cs);
      ctab[idx] = make_float2(cs, sn);
    }
    return;
  }
  __shared__ float tile[32][33];
  const float* src; unsigned short* dst; int N, t;
  if (id < 4096)       { src = wq; dst = wqt; N = 2048; t = id; }
  else if (id < 8192)  { src = wo; dst = wot; N = 2048; t = id - 4096; }
  else if (id < 9216)  { src = wk; dst = wkt; N = 512;  t = id - 8192; }
  else                 { src = wv; dst = wvt; N = 512;  t = id - 9216; }
  const int K = 2048;
  int ntx = N >> 5;
  int bn = (t % ntx) * 32, bk = (t / ntx) * 32;
  int tx = threadIdx.x & 31, ty = threadIdx.x >> 5;
#pragma unroll
  for (int i = 0; i < 32; i += 8)
    tile[ty + i][tx] = src[(size_t)(bk + ty + i) * N + bn + tx];
  __syncthreads();
#pragma unroll
  for (int i = 0; i < 32; i += 8)
    dst[(size_t)(bn + ty + i) * K + bk + tx] = f2bf(tile[tx][ty + i]);
}

// ---------- bf16 MFMA GEMM with fused epilogues (unchanged from R8/R11) ----------
__global__ __launch_bounds__(256) void k_gemm_bf16(const unsigned short* __restrict__ A,
                                                   const unsigned short* __restrict__ Bt,
                                                   float* __restrict__ C,
                                                   unsigned short* __restrict__ Qd,
                                                   unsigned short* __restrict__ Kd,
                                                   unsigned short* __restrict__ VT,
                                                   const float2* __restrict__ ctab,
                                                   int M, int N, int K, int fuse) {
  __shared__ short sA[2][128 * 64];
  __shared__ short sB[2][64 * 64];
  int tid = threadIdx.x;
  int lane = tid & 63, wid = tid >> 6;
  int wr = wid >> 1, wc = wid & 1;

  int gx = gridDim.x, nwg = gx * gridDim.y;
  int flat = blockIdx.y * gx + blockIdx.x;
  int l = (flat & 7) * (nwg >> 3) + (flat >> 3);
  int bx = l % gx, by = l / gx;
  int m0 = by * 128, n0 = bx * 64;

  f32x4 acc[4][2] = {};

  int srcCol = (((tid & 7) ^ ((tid >> 3) & 7)) << 3);
  int rA = tid >> 3;
  const unsigned short* Ag = A + (size_t)(m0 + rA) * K + srcCol;
  const unsigned short* Bg = Bt + (size_t)(n0 + rA) * K + srcCol;
  int wb = (tid & ~63) * 8;            // wave-uniform LDS base (shorts)

  int g = lane >> 4, fr = lane & 15, sw = fr & 7;

#define STAGE_G(buf, kof) do { \
    gl_lds16(Ag + (kof),                    &sA[buf][wb]); \
    gl_lds16(Ag + 32 * (size_t)K + (kof),   &sA[buf][2048 + wb]); \
    gl_lds16(Ag + 64 * (size_t)K + (kof),   &sA[buf][4096 + wb]); \
    gl_lds16(Ag + 96 * (size_t)K + (kof),   &sA[buf][6144 + wb]); \
    gl_lds16(Bg + (kof),                    &sB[buf][wb]); \
    gl_lds16(Bg + 32 * (size_t)K + (kof),   &sB[buf][2048 + wb]); \
  } while (0)

  int nt = K >> 6;
  STAGE_G(0, 0);
  __syncthreads();

  int cur = 0;
  for (int t = 0; t < nt; t++) {
    if (t + 1 < nt) STAGE_G(cur ^ 1, (size_t)((t + 1) << 6));
    const short* sAc = sA[cur];
    const short* sBc = sB[cur];
#pragma unroll
    for (int kk = 0; kk < 2; kk++) {
      int so = ((((kk << 2) + g) ^ sw) << 3);
      short8 af[4], bf2[2];
#pragma unroll
      for (int x = 0; x < 4; x++)
        af[x] = *(const short8*)(sAc + (wr * 64 + x * 16 + fr) * 64 + so);
#pragma unroll
      for (int ni = 0; ni < 2; ni++)
        bf2[ni] = *(const short8*)(sBc + (wc * 32 + ni * 16 + fr) * 64 + so);
#pragma unroll
      for (int x = 0; x < 4; x++)
#pragma unroll
        for (int ni = 0; ni < 2; ni++)
          acc[x][ni] = __builtin_amdgcn_mfma_f32_16x16x32_bf16(af[x], bf2[ni], acc[x][ni], 0, 0, 0);
    }
    __syncthreads();
    cur ^= 1;
  }
#undef STAGE_G

  int rb = m0 + wr * 64 + (g << 2);
  if (!fuse) {
#pragma unroll
    for (int ni = 0; ni < 2; ni++) {
      int col = n0 + wc * 32 + ni * 16 + fr;
#pragma unroll
      for (int x = 0; x < 4; x++)
#pragma unroll
        for (int j = 0; j < 4; j++)
          C[(size_t)(rb + x * 16 + j) * N + col] = acc[x][ni][j];
    }
    return;
  }

  const float QAMP = 0.12751742836257666f;  // 1/sqrt(128) * log2(e)
#pragma unroll
  for (int ni = 0; ni < 2; ni++) {
    int col = n0 + wc * 32 + ni * 16 + fr;
    if (col >= 2560) {
#pragma unroll
      for (int x = 0; x < 4; x++) {
        ushort4 pk;
        pk.x = f2bf(acc[x][ni][0]); pk.y = f2bf(acc[x][ni][1]);
        pk.z = f2bf(acc[x][ni][2]); pk.w = f2bf(acc[x][ni][3]);
        *(ushort4*)(VT + (size_t)(col - 2560) * 2048 + rb + x * 16) = pk;
      }
    } else {
      int ipair = (col & 127) >> 1;
      bool even = (col & 1) == 0;
      bool isQ = col < 2048;
      unsigned short* dst = isQ ? Qd : Kd;
      int stride = isQ ? 2048 : 512;
      int dcol = isQ ? col : (col - 2048);
      float amp = isQ ? QAMP : 1.0f;
#pragma unroll
      for (int x = 0; x < 4; x++) {
        f32x4 a = acc[x][ni];
        float p0 = __shfl_xor(a[0], 1), p1 = __shfl_xor(a[1], 1);
        float p2 = __shfl_xor(a[2], 1), p3 = __shfl_xor(a[3], 1);
        float pv[4] = {p0, p1, p2, p3};
#pragma unroll
        for (int j = 0; j < 4; j++) {
          int r = rb + x * 16 + j;
          float2 cs = ctab[r * 64 + ipair];
          float o = even ? (a[j] * cs.x - pv[j] * cs.y)
                         : (pv[j] * cs.y + a[j] * cs.x);
          dst[(size_t)r * stride + dcol] = f2bf(o * amp);
        }
      }
    }
  }
}

// ---------- bf16 MFMA flash attention, GQA, causal ----------
// 512 blocks (32,16) x 512 thr: qb = (h<8)? x : 31-x (complementary co-resident
// pairs: 33 tiles/CU constant). 8 waves = 4 q-row-groups x 2 KV parities;
// exact f32 parity merge via LDS. R14: P stays IN REGISTERS (cvt_pk uint2 +
// static 4-sublane shfl permutation to PV A-fragments) -> sP eliminated,
// LDS 90.1 -> 71.7 KB -> 2 blocks/CU (16 waves).
#define KSTR 136
#define VSTR 72
__global__ __launch_bounds__(512) void k_attn_mfma(const unsigned short* __restrict__ Qb,
                                                   const unsigned short* __restrict__ Kb,
                                                   const unsigned short* __restrict__ Vt,
                                                   unsigned short* __restrict__ O) {
  __shared__ short sK[2][64 * KSTR];   // merge scratch: f32 onum[4][16][128]
  __shared__ short sV[2][128 * VSTR];  // merge scratch: f32 mlb[4][16][2]
  int h = blockIdx.y;
  int x = blockIdx.x;
  int qb = (h < 8) ? x : (31 - x);
  int q0 = qb * 64;
  int kvh = h >> 2;
  int tid = threadIdx.x, lane = tid & 63, w8 = tid >> 6;
  int g4 = w8 & 3;          // q-row group
  int p = w8 >> 2;          // KV parity
  int fr = lane & 15, g = lane >> 4, kq = g << 3;

  short8 qf[4];
  {
    const unsigned short* qrow = Qb + (size_t)(q0 + g4 * 16 + fr) * 2048 + h * 128 + kq;
#pragma unroll
    for (int ko = 0; ko < 4; ko++) qf[ko] = *(const short8*)(qrow + ko * 32);
  }

  f32x4 oacc[8];
#pragma unroll
  for (int nd = 0; nd < 8; nd++) oacc[nd] = (f32x4){0.f, 0.f, 0.f, 0.f};
  float m_i = -3e38f;
  float l_i = 0.f;

  // staging: threads 0-255 -> buf 0 (even tiles), 256-511 -> buf 1 (odd)
  int half = tid >> 8;
  int t2 = tid & 255;
  int skr = t2 >> 2, skc = (t2 & 3) << 5;
  int svd = t2 >> 1, svc = (t2 & 1) << 5;
  const unsigned short* Kbase = Kb + (size_t)kvh * 128 + skc;
  const unsigned short* Vbase = Vt + (size_t)(kvh * 128 + svd) * 2048 + svc;
  int kdOff = skr * KSTR + skc;
  int vdOff = svd * VSTR + svc;

  short8 kreg[4], vreg[4];
  if (half <= qb) {   // stage tile `half` into buf `half`
    const short8* ks = (const short8*)(Kbase + (size_t)(half * 64 + skr) * 512);
    const short8* vs = (const short8*)(Vbase + half * 64);
#pragma unroll
    for (int j = 0; j < 4; j++) { kreg[j] = ks[j]; vreg[j] = vs[j]; }
    short* kd = sK[half] + kdOff; short* vd = sV[half] + vdOff;
#pragma unroll
    for (int j = 0; j < 4; j++) { *(short8*)(kd + j * 8) = kreg[j]; *(short8*)(vd + j * 8) = vreg[j]; }
  }
  if (2 + half <= qb) {   // prefetch tile 2+half
    const short8* ks = (const short8*)(Kbase + (size_t)((2 + half) * 64 + skr) * 512);
    const short8* vs = (const short8*)(Vbase + (2 + half) * 64);
#pragma unroll
    for (int j = 0; j < 4; j++) { kreg[j] = ks[j]; vreg[j] = vs[j]; }
  }
  __syncthreads();

  int qrowS = q0 + g4 * 16 + fr;
  int nIter = (qb + 2) >> 1;

  // P redistribution sources (static): lo from lane fr+32*(g&1), hi = +16;
  // register select rsel = g>>1.
  int srcA = fr + ((g & 1) << 5);
  int srcB = srcA + 16;
  int rsel = g >> 1;

  for (int i = 0; i < nIter; i++) {
    int t = 2 * i + p;
    if (t <= qb) {
      const short* sKc = sK[p];
      const short* sVc = sV[p];

      // S^T = K Q^T : lane (fr,g), reg (ni,j) = S[q=fr][k = ni*16 + g*4 + j]
      f32x4 sacc[4];
#pragma unroll
      for (int ni = 0; ni < 4; ni++) sacc[ni] = (f32x4){0.f, 0.f, 0.f, 0.f};
      __builtin_amdgcn_s_setprio(1);
#pragma unroll
      for (int ko = 0; ko < 4; ko++)
#pragma unroll
        for (int ni = 0; ni < 4; ni++) {
          short8 kf = *(const short8*)(sKc + (ni * 16 + fr) * KSTR + kq + ko * 32);
          sacc[ni] = __builtin_amdgcn_mfma_f32_16x16x32_bf16(kf, qf[ko], sacc[ni], 0, 0, 0);
        }
      __builtin_amdgcn_s_setprio(0);

      if (t == qb) {  // diagonal tile: causal mask
        int k0 = t * 64;
#pragma unroll
        for (int ni = 0; ni < 4; ni++) {
          int kc = k0 + ni * 16 + (g << 2);
#pragma unroll
          for (int j = 0; j < 4; j++)
            if (kc + j > qrowS) sacc[ni][j] = -3e38f;
        }
      }

      // row max: balanced tree, then 2 cross-lane hops
      float t0m = fmaxf(fmaxf(sacc[0][0], sacc[0][1]), fmaxf(sacc[0][2], sacc[0][3]));
      float t1m = fmaxf(fmaxf(sacc[1][0], sacc[1][1]), fmaxf(sacc[1][2], sacc[1][3]));
      float t2m = fmaxf(fmaxf(sacc[2][0], sacc[2][1]), fmaxf(sacc[2][2], sacc[2][3]));
      float t3m = fmaxf(fmaxf(sacc[3][0], sacc[3][1]), fmaxf(sacc[3][2], sacc[3][3]));
      float tm = fmaxf(fmaxf(t0m, t1m), fmaxf(t2m, t3m));
      tm = fmaxf(tm, __shfl_xor(tm, 16));
      tm = fmaxf(tm, __shfl_xor(tm, 32));

      if (!__all(tm <= m_i + 8.0f)) {
        float mn = fmaxf(m_i, tm);
        float sc = exp2f(m_i - mn);
        m_i = mn;
        float scj[4];
#pragma unroll
        for (int j = 0; j < 4; j++) scj[j] = __shfl(sc, (g << 2) + j);
#pragma unroll
        for (int nd = 0; nd < 8; nd++)
#pragma unroll
          for (int j = 0; j < 4; j++) oacc[nd][j] *= scj[j];
        l_i *= sc;
      }

      // P = exp2(S - m), packed to bf16 pairs, kept in registers
      uint2 Pk[4];
      float ps = 0.f;
#pragma unroll
      for (int ni = 0; ni < 4; ni++) {
        float p0 = exp2f(sacc[ni][0] - m_i);
        float p1 = exp2f(sacc[ni][1] - m_i);
        float p2 = exp2f(sacc[ni][2] - m_i);
        float p3 = exp2f(sacc[ni][3] - m_i);
        ps += (p0 + p1) + (p2 + p3);
        Pk[ni].x = cvt_pk_bf16(p0, p1);
        Pk[ni].y = cvt_pk_bf16(p2, p3);
      }
      ps += __shfl_xor(ps, 16);
      ps += __shfl_xor(ps, 32);
      l_i += ps;

      // O += P V ; PA fragments assembled in-register via static shfl perm
      __builtin_amdgcn_s_setprio(1);
#pragma unroll
      for (int ks = 0; ks < 2; ks++) {
        uint2 A0 = shfl64(Pk[2 * ks],     srcA);
        uint2 A1 = shfl64(Pk[2 * ks + 1], srcA);
        uint2 B0 = shfl64(Pk[2 * ks],     srcB);
        uint2 B1 = shfl64(Pk[2 * ks + 1], srcB);
        union { unsigned int u[4]; short8 s; } pc;
        pc.u[0] = rsel ? A1.x : A0.x;
        pc.u[1] = rsel ? A1.y : A0.y;
        pc.u[2] = rsel ? B1.x : B0.x;
        pc.u[3] = rsel ? B1.y : B0.y;
        short8 pa = pc.s;
#pragma unroll
        for (int nd = 0; nd < 8; nd++) {
          short8 vb = *(const short8*)(sVc + (nd * 16 + fr) * VSTR + kq + ks * 32);
          oacc[nd] = __builtin_amdgcn_mfma_f32_16x16x32_bf16(pa, vb, oacc[nd], 0, 0, 0);
        }
      }
      __builtin_amdgcn_s_setprio(0);
    }

    if (i + 1 < nIter) {
      __syncthreads();   // all waves done reading both buffers
      int tn = 2 * (i + 1) + half;
      if (tn <= qb) {
        short* kd = sK[half] + kdOff; short* vd = sV[half] + vdOff;
#pragma unroll
        for (int j = 0; j < 4; j++) { *(short8*)(kd + j * 8) = kreg[j]; *(short8*)(vd + j * 8) = vreg[j]; }
      }
      int tl = 2 * (i + 2) + half;
      if (tl <= qb) {
        const short8* ks = (const short8*)(Kbase + (size_t)(tl * 64 + skr) * 512);
        const short8* vs = (const short8*)(Vbase + tl * 64);
#pragma unroll
        for (int j = 0; j < 4; j++) { kreg[j] = ks[j]; vreg[j] = vs[j]; }
      }
      __syncthreads();   // buffers ready
    }
  }

  // ---- merge parity groups (exact f32) ----
  __syncthreads();   // main-loop LDS reads done; reuse sK/sV as scratch
  float* onum = (float*)sK;   // [4 groups][16 rows][128 cols]
  float* mlb = (float*)sV;    // [4 groups][16 rows][2]
  if (p == 1) {
    int r0 = g4 * 16;
#pragma unroll
    for (int j = 0; j < 4; j++)
#pragma unroll
      for (int nd = 0; nd < 8; nd++)
        onum[(r0 + (g << 2) + j) * 128 + nd * 16 + fr] = oacc[nd][j];
    if (g == 0) {
      mlb[(r0 + fr) * 2] = m_i;
      mlb[(r0 + fr) * 2 + 1] = l_i;
    }
  }
  __syncthreads();
  if (p == 0) {
    int orow = q0 + g4 * 16 + (g << 2);
    int r0 = g4 * 16;
#pragma unroll
    for (int j = 0; j < 4; j++) {
      int rl = (g << 2) + j;
      float ma = __shfl(m_i, rl);
      float la = __shfl(l_i, rl);
      float mb = mlb[(r0 + rl) * 2];
      float lb = mlb[(r0 + rl) * 2 + 1];
      float M = fmaxf(ma, mb);
      float wa = exp2f(ma - M), wbv = exp2f(mb - M);
      float inv = 1.0f / (wa * la + wbv * lb);
#pragma unroll
      for (int nd = 0; nd < 8; nd++) {
        float ob = onum[(r0 + rl) * 128 + nd * 16 + fr];
        O[(size_t)(orow + j) * 2048 + h * 128 + nd * 16 + fr] =
            f2bf((wa * oacc[nd][j] + wbv * ob) * inv);
      }
    }
  }
}

extern "C" void kernel_launch(void* const* d_in, const int* in_sizes, int n_in,
                              void* d_out, int out_size, void* d_ws, size_t ws_size,
                              hipStream_t stream) {
  const float* hs = (const float*)d_in[0];
  const float* wq = (const float*)d_in[1];
  const float* wk = (const float*)d_in[2];
  const float* wv = (const float*)d_in[3];
  const float* wo = (const float*)d_in[4];
  char* ws = (char*)d_ws;

  unsigned short* hb   = (unsigned short*)(ws);             // 2048x2048 bf16; later ao
  unsigned short* wqt  = (unsigned short*)(ws + 8388608);   // 2048x2048 bf16
  unsigned short* wkt  = (unsigned short*)(ws + 16777216);  // 512x2048 bf16
  unsigned short* wvt  = (unsigned short*)(ws + 18874368);  // 512x2048 bf16
  unsigned short* wot  = (unsigned short*)(ws + 20971520);  // 2048x2048 bf16
  unsigned short* q_bf = (unsigned short*)(ws + 29360128);  // 2048x2048 bf16
  unsigned short* k_bf = (unsigned short*)(ws + 37748736);  // 2048x512 bf16
  unsigned short* vt_bf= (unsigned short*)(ws + 39845888);  // 512x2048 bf16
  float2* ctab         = (float2*)(ws + 41943040);          // 2048x64 float2 (1 MB)
  unsigned short* ao   = hb;
  float* out = (float*)d_out;

  // fused prep: 10240 transpose blocks + 4096 f2bf blocks + 512 sincos blocks
  k_prep<<<14848, 256, 0, stream>>>(wq, wk, wv, wo, hs, wqt, wkt, wvt, wot, hb, ctab);

  // fused QKV projection: epilogue applies rope -> q_bf/k_bf, V -> vt_bf (transposed)
  k_gemm_bf16<<<dim3(48, 16), 256, 0, stream>>>(hb, wqt, (float*)nullptr,
                                                q_bf, k_bf, vt_bf, ctab,
                                                2048, 3072, 2048, 1);

  // attention: (32,16) x 512 threads, complementary pairs, 2 blocks/CU
  k_attn_mfma<<<dim3(32, 16), 512, 0, stream>>>(q_bf, k_bf, vt_bf, ao);

  // output projection: plain f32 epilogue
  k_gemm_bf16<<<dim3(32, 16), 256, 0, stream>>>(ao, wot, out,
                                                (unsigned short*)nullptr,
                                                (unsigned short*)nullptr,
                                                (unsigned short*)nullptr,
                                                (const float2*)nullptr,
                                                2048, 2048, 2048, 0);
}

// Round 15
// 135.318 us; speedup vs baseline: 1.2564x; 1.2564x over previous
//
#include <hip/hip_runtime.h>
#include <cstdint>

typedef __attribute__((ext_vector_type(8))) short short8;
typedef __attribute__((ext_vector_type(4))) float f32x4;

static __device__ __forceinline__ unsigned short f2bf(float x) {
  union { float f; unsigned int u; } c; c.f = x;
  unsigned int u = c.u;
  unsigned int r = (u + 0x7fffu + ((u >> 16) & 1u)) >> 16;  // RNE
  return (unsigned short)r;
}

static __device__ __forceinline__ unsigned int cvt_pk_bf16(float a, float b) {
  unsigned int r;
  asm("v_cvt_pk_bf16_f32 %0, %1, %2" : "=v"(r) : "v"(a), "v"(b));
  return r;
}

static __device__ __forceinline__ void gl_lds16(const void* g, void* l) {
  __builtin_amdgcn_global_load_lds((const __attribute__((address_space(1))) void*)g,
                                   (__attribute__((address_space(3))) void*)l, 16, 0, 0);
}

// ---------- fused prep: weight transposes + hidden f32->bf16 + sincos table ----------
__global__ __launch_bounds__(256) void k_prep(const float* __restrict__ wq,
                                              const float* __restrict__ wk,
                                              const float* __restrict__ wv,
                                              const float* __restrict__ wo,
                                              const float* __restrict__ hs,
                                              unsigned short* __restrict__ wqt,
                                              unsigned short* __restrict__ wkt,
                                              unsigned short* __restrict__ wvt,
                                              unsigned short* __restrict__ wot,
                                              unsigned short* __restrict__ hb,
                                              float2* __restrict__ ctab) {
  int id = blockIdx.x;
  if (id >= 10240) {
    if (id < 14336) {          // hidden f32 -> bf16 (float4 per thread)
      int i = (id - 10240) * 256 + threadIdx.x;
      float4 v = reinterpret_cast<const float4*>(hs)[i];
      ushort4 o;
      o.x = f2bf(v.x); o.y = f2bf(v.y); o.z = f2bf(v.z); o.w = f2bf(v.w);
      reinterpret_cast<ushort4*>(hb)[i] = o;
    } else {                   // sincos table (2048*64)
      int idx = (id - 14336) * 256 + threadIdx.x;
      int s = idx >> 6, i = idx & 63;
      float freq = powf(10000.0f, -(float)i / 64.0f);
      float sn, cs;
      sincosf((float)s * freq, &sn, &cs);
      ctab[idx] = make_float2(cs, sn);
    }
    return;
  }
  __shared__ float tile[32][33];
  const float* src; unsigned short* dst; int N, t;
  if (id < 4096)       { src = wq; dst = wqt; N = 2048; t = id; }
  else if (id < 8192)  { src = wo; dst = wot; N = 2048; t = id - 4096; }
  else if (id < 9216)  { src = wk; dst = wkt; N = 512;  t = id - 8192; }
  else                 { src = wv; dst = wvt; N = 512;  t = id - 9216; }
  const int K = 2048;
  int ntx = N >> 5;
  int bn = (t % ntx) * 32, bk = (t / ntx) * 32;
  int tx = threadIdx.x & 31, ty = threadIdx.x >> 5;
#pragma unroll
  for (int i = 0; i < 32; i += 8)
    tile[ty + i][tx] = src[(size_t)(bk + ty + i) * N + bn + tx];
  __syncthreads();
#pragma unroll
  for (int i = 0; i < 32; i += 8)
    dst[(size_t)(bn + ty + i) * K + bk + tx] = f2bf(tile[tx][ty + i]);
}

// ---------- bf16 MFMA GEMM with fused epilogues (R8/R11 proven) ----------
__global__ __launch_bounds__(256) void k_gemm_bf16(const unsigned short* __restrict__ A,
                                                   const unsigned short* __restrict__ Bt,
                                                   float* __restrict__ C,
                                                   unsigned short* __restrict__ Qd,
                                                   unsigned short* __restrict__ Kd,
                                                   unsigned short* __restrict__ VT,
                                                   const float2* __restrict__ ctab,
                                                   int M, int N, int K, int fuse) {
  __shared__ short sA[2][128 * 64];
  __shared__ short sB[2][64 * 64];
  int tid = threadIdx.x;
  int lane = tid & 63, wid = tid >> 6;
  int wr = wid >> 1, wc = wid & 1;

  int gx = gridDim.x, nwg = gx * gridDim.y;
  int flat = blockIdx.y * gx + blockIdx.x;
  int l = (flat & 7) * (nwg >> 3) + (flat >> 3);
  int bx = l % gx, by = l / gx;
  int m0 = by * 128, n0 = bx * 64;

  f32x4 acc[4][2] = {};

  int srcCol = (((tid & 7) ^ ((tid >> 3) & 7)) << 3);
  int rA = tid >> 3;
  const unsigned short* Ag = A + (size_t)(m0 + rA) * K + srcCol;
  const unsigned short* Bg = Bt + (size_t)(n0 + rA) * K + srcCol;
  int wb = (tid & ~63) * 8;            // wave-uniform LDS base (shorts)

  int g = lane >> 4, fr = lane & 15, sw = fr & 7;

#define STAGE_G(buf, kof) do { \
    gl_lds16(Ag + (kof),                    &sA[buf][wb]); \
    gl_lds16(Ag + 32 * (size_t)K + (kof),   &sA[buf][2048 + wb]); \
    gl_lds16(Ag + 64 * (size_t)K + (kof),   &sA[buf][4096 + wb]); \
    gl_lds16(Ag + 96 * (size_t)K + (kof),   &sA[buf][6144 + wb]); \
    gl_lds16(Bg + (kof),                    &sB[buf][wb]); \
    gl_lds16(Bg + 32 * (size_t)K + (kof),   &sB[buf][2048 + wb]); \
  } while (0)

  int nt = K >> 6;
  STAGE_G(0, 0);
  __syncthreads();

  int cur = 0;
  for (int t = 0; t < nt; t++) {
    if (t + 1 < nt) STAGE_G(cur ^ 1, (size_t)((t + 1) << 6));
    const short* sAc = sA[cur];
    const short* sBc = sB[cur];
#pragma unroll
    for (int kk = 0; kk < 2; kk++) {
      int so = ((((kk << 2) + g) ^ sw) << 3);
      short8 af[4], bf2[2];
#pragma unroll
      for (int x = 0; x < 4; x++)
        af[x] = *(const short8*)(sAc + (wr * 64 + x * 16 + fr) * 64 + so);
#pragma unroll
      for (int ni = 0; ni < 2; ni++)
        bf2[ni] = *(const short8*)(sBc + (wc * 32 + ni * 16 + fr) * 64 + so);
#pragma unroll
      for (int x = 0; x < 4; x++)
#pragma unroll
        for (int ni = 0; ni < 2; ni++)
          acc[x][ni] = __builtin_amdgcn_mfma_f32_16x16x32_bf16(af[x], bf2[ni], acc[x][ni], 0, 0, 0);
    }
    __syncthreads();
    cur ^= 1;
  }
#undef STAGE_G

  int rb = m0 + wr * 64 + (g << 2);
  if (!fuse) {
#pragma unroll
    for (int ni = 0; ni < 2; ni++) {
      int col = n0 + wc * 32 + ni * 16 + fr;
#pragma unroll
      for (int x = 0; x < 4; x++)
#pragma unroll
        for (int j = 0; j < 4; j++)
          C[(size_t)(rb + x * 16 + j) * N + col] = acc[x][ni][j];
    }
    return;
  }

  const float QAMP = 0.12751742836257666f;  // 1/sqrt(128) * log2(e)
#pragma unroll
  for (int ni = 0; ni < 2; ni++) {
    int col = n0 + wc * 32 + ni * 16 + fr;
    if (col >= 2560) {
#pragma unroll
      for (int x = 0; x < 4; x++) {
        ushort4 pk;
        pk.x = f2bf(acc[x][ni][0]); pk.y = f2bf(acc[x][ni][1]);
        pk.z = f2bf(acc[x][ni][2]); pk.w = f2bf(acc[x][ni][3]);
        *(ushort4*)(VT + (size_t)(col - 2560) * 2048 + rb + x * 16) = pk;
      }
    } else {
      int ipair = (col & 127) >> 1;
      bool even = (col & 1) == 0;
      bool isQ = col < 2048;
      unsigned short* dst = isQ ? Qd : Kd;
      int stride = isQ ? 2048 : 512;
      int dcol = isQ ? col : (col - 2048);
      float amp = isQ ? QAMP : 1.0f;
#pragma unroll
      for (int x = 0; x < 4; x++) {
        f32x4 a = acc[x][ni];
        float p0 = __shfl_xor(a[0], 1), p1 = __shfl_xor(a[1], 1);
        float p2 = __shfl_xor(a[2], 1), p3 = __shfl_xor(a[3], 1);
        float pv[4] = {p0, p1, p2, p3};
#pragma unroll
        for (int j = 0; j < 4; j++) {
          int r = rb + x * 16 + j;
          float2 cs = ctab[r * 64 + ipair];
          float o = even ? (a[j] * cs.x - pv[j] * cs.y)
                         : (pv[j] * cs.y + a[j] * cs.x);
          dst[(size_t)r * stride + dcol] = f2bf(o * amp);
        }
      }
    }
  }
}

// ---------- bf16 MFMA flash attention, GQA, causal (R13 proven-best) ----------
// 256 blocks x 512 thr, constant work per block: block (pi,h) processes q-tile
// (31-pi) then q-tile (pi) SEQUENTIALLY -> 17-18 parity-iters for every block.
// 8 waves = 4 q-row-groups x 2 KV parities; exact f32 merge via LDS per sub-tile.
#define KSTR 136
#define VSTR 72
#define PSTR 72
__global__ __launch_bounds__(512) void k_attn_mfma(const unsigned short* __restrict__ Qb,
                                                   const unsigned short* __restrict__ Kb,
                                                   const unsigned short* __restrict__ Vt,
                                                   unsigned short* __restrict__ O) {
  __shared__ short sK[2][64 * KSTR];   // merge scratch: f32 onum[4][16][128]
  __shared__ short sV[2][128 * VSTR];  // merge scratch: f32 mlb[4][16][2]
  __shared__ short sP[8][16 * PSTR];
  int b = blockIdx.x;
  int pi = b >> 4;          // 0..15
  int h = b & 15;
  int kvh = h >> 2;
  int tid = threadIdx.x, lane = tid & 63, w8 = tid >> 6;
  int g4 = w8 & 3;          // q-row group
  int p = w8 >> 2;          // KV parity
  int fr = lane & 15, g = lane >> 4, kq = g << 3;

  int half = tid >> 8;      // staging: threads 0-255 -> buf 0, 256-511 -> buf 1
  int t2 = tid & 255;
  int skr = t2 >> 2, skc = (t2 & 3) << 5;
  int svd = t2 >> 1, svc = (t2 & 1) << 5;
  const unsigned short* Kbase = Kb + (size_t)kvh * 128 + skc;
  const unsigned short* Vbase = Vt + (size_t)(kvh * 128 + svd) * 2048 + svc;
  short* pw = (short*)sP[w8];
  int kdOff = skr * KSTR + skc;
  int vdOff = svd * VSTR + svc;

  for (int sub = 0; sub < 2; sub++) {
    int qb = sub ? pi : (31 - pi);
    int q0 = qb * 64;

    short8 qf[4];
    {
      const unsigned short* qrow = Qb + (size_t)(q0 + g4 * 16 + fr) * 2048 + h * 128 + kq;
#pragma unroll
      for (int ko = 0; ko < 4; ko++) qf[ko] = *(const short8*)(qrow + ko * 32);
    }

    f32x4 oacc[8];
#pragma unroll
    for (int nd = 0; nd < 8; nd++) oacc[nd] = (f32x4){0.f, 0.f, 0.f, 0.f};
    float m_i = -3e38f;
    float l_i = 0.f;

    if (sub) __syncthreads();   // previous merge's scratch reads done

    short8 kreg[4], vreg[4];
    if (half <= qb) {   // stage tile `half` into buf `half`
      const short8* ks = (const short8*)(Kbase + (size_t)(half * 64 + skr) * 512);
      const short8* vs = (const short8*)(Vbase + half * 64);
#pragma unroll
      for (int j = 0; j < 4; j++) { kreg[j] = ks[j]; vreg[j] = vs[j]; }
      short* kd = sK[half] + kdOff; short* vd = sV[half] + vdOff;
#pragma unroll
      for (int j = 0; j < 4; j++) { *(short8*)(kd + j * 8) = kreg[j]; *(short8*)(vd + j * 8) = vreg[j]; }
    }
    if (2 + half <= qb) {   // prefetch tile 2+half
      const short8* ks = (const short8*)(Kbase + (size_t)((2 + half) * 64 + skr) * 512);
      const short8* vs = (const short8*)(Vbase + (2 + half) * 64);
#pragma unroll
      for (int j = 0; j < 4; j++) { kreg[j] = ks[j]; vreg[j] = vs[j]; }
    }
    __syncthreads();

    int qrowS = q0 + g4 * 16 + fr;
    int nIter = (qb + 2) >> 1;

    for (int i = 0; i < nIter; i++) {
      int t = 2 * i + p;
      if (t <= qb) {
        const short* sKc = sK[p];
        const short* sVc = sV[p];

        f32x4 sacc[4];
#pragma unroll
        for (int ni = 0; ni < 4; ni++) sacc[ni] = (f32x4){0.f, 0.f, 0.f, 0.f};
        __builtin_amdgcn_s_setprio(1);
#pragma unroll
        for (int ko = 0; ko < 4; ko++)
#pragma unroll
          for (int ni = 0; ni < 4; ni++) {
            short8 kf = *(const short8*)(sKc + (ni * 16 + fr) * KSTR + kq + ko * 32);
            sacc[ni] = __builtin_amdgcn_mfma_f32_16x16x32_bf16(kf, qf[ko], sacc[ni], 0, 0, 0);
          }
        __builtin_amdgcn_s_setprio(0);

        if (t == qb) {  // diagonal tile: causal mask
          int k0 = t * 64;
#pragma unroll
          for (int ni = 0; ni < 4; ni++) {
            int kc = k0 + ni * 16 + (g << 2);
#pragma unroll
            for (int j = 0; j < 4; j++)
              if (kc + j > qrowS) sacc[ni][j] = -3e38f;
          }
        }

        float t0m = fmaxf(fmaxf(sacc[0][0], sacc[0][1]), fmaxf(sacc[0][2], sacc[0][3]));
        float t1m = fmaxf(fmaxf(sacc[1][0], sacc[1][1]), fmaxf(sacc[1][2], sacc[1][3]));
        float t2m = fmaxf(fmaxf(sacc[2][0], sacc[2][1]), fmaxf(sacc[2][2], sacc[2][3]));
        float t3m = fmaxf(fmaxf(sacc[3][0], sacc[3][1]), fmaxf(sacc[3][2], sacc[3][3]));
        float tm = fmaxf(fmaxf(t0m, t1m), fmaxf(t2m, t3m));
        tm = fmaxf(tm, __shfl_xor(tm, 16));
        tm = fmaxf(tm, __shfl_xor(tm, 32));

        if (!__all(tm <= m_i + 8.0f)) {
          float mn = fmaxf(m_i, tm);
          float sc = exp2f(m_i - mn);
          m_i = mn;
          float scj[4];
#pragma unroll
          for (int j = 0; j < 4; j++) scj[j] = __shfl(sc, (g << 2) + j);
#pragma unroll
          for (int nd = 0; nd < 8; nd++)
#pragma unroll
            for (int j = 0; j < 4; j++) oacc[nd][j] *= scj[j];
          l_i *= sc;
        }

        float ps = 0.f;
#pragma unroll
        for (int ni = 0; ni < 4; ni++) {
          float p0 = exp2f(sacc[ni][0] - m_i);
          float p1 = exp2f(sacc[ni][1] - m_i);
          float p2 = exp2f(sacc[ni][2] - m_i);
          float p3 = exp2f(sacc[ni][3] - m_i);
          ps += (p0 + p1) + (p2 + p3);
          uint2 pk;
          pk.x = cvt_pk_bf16(p0, p1);
          pk.y = cvt_pk_bf16(p2, p3);
          *(uint2*)(pw + fr * PSTR + ni * 16 + (g << 2)) = pk;
        }
        ps += __shfl_xor(ps, 16);
        ps += __shfl_xor(ps, 32);
        l_i += ps;

        __builtin_amdgcn_s_setprio(1);
#pragma unroll
        for (int ks = 0; ks < 2; ks++) {
          short8 pa = *(const short8*)(pw + fr * PSTR + kq + ks * 32);
#pragma unroll
          for (int nd = 0; nd < 8; nd++) {
            short8 vb = *(const short8*)(sVc + (nd * 16 + fr) * VSTR + kq + ks * 32);
            oacc[nd] = __builtin_amdgcn_mfma_f32_16x16x32_bf16(pa, vb, oacc[nd], 0, 0, 0);
          }
        }
        __builtin_amdgcn_s_setprio(0);
      }

      if (i + 1 < nIter) {
        __syncthreads();   // all waves done reading both buffers
        int tn = 2 * (i + 1) + half;
        if (tn <= qb) {
          short* kd = sK[half] + kdOff; short* vd = sV[half] + vdOff;
#pragma unroll
          for (int j = 0; j < 4; j++) { *(short8*)(kd + j * 8) = kreg[j]; *(short8*)(vd + j * 8) = vreg[j]; }
        }
        int tl = 2 * (i + 2) + half;
        if (tl <= qb) {
          const short8* ks = (const short8*)(Kbase + (size_t)(tl * 64 + skr) * 512);
          const short8* vs = (const short8*)(Vbase + tl * 64);
#pragma unroll
          for (int j = 0; j < 4; j++) { kreg[j] = ks[j]; vreg[j] = vs[j]; }
        }
        __syncthreads();   // buffers ready
      }
    }

    // ---- merge parity groups (exact f32) ----
    __syncthreads();   // main-loop LDS reads done; reuse sK/sV as scratch
    float* onum = (float*)sK;   // [4 groups][16 rows][128 cols]
    float* mlb = (float*)sV;    // [4 groups][16 rows][2]
    if (p == 1) {
      int r0 = g4 * 16;
#pragma unroll
      for (int j = 0; j < 4; j++)
#pragma unroll
        for (int nd = 0; nd < 8; nd++)
          onum[(r0 + (g << 2) + j) * 128 + nd * 16 + fr] = oacc[nd][j];
      if (g == 0) {
        mlb[(r0 + fr) * 2] = m_i;
        mlb[(r0 + fr) * 2 + 1] = l_i;
      }
    }
    __syncthreads();
    if (p == 0) {
      int orow = q0 + g4 * 16 + (g << 2);
      int r0 = g4 * 16;
#pragma unroll
      for (int j = 0; j < 4; j++) {
        int rl = (g << 2) + j;
        float ma = __shfl(m_i, rl);
        float la = __shfl(l_i, rl);
        float mb = mlb[(r0 + rl) * 2];
        float lb = mlb[(r0 + rl) * 2 + 1];
        float M = fmaxf(ma, mb);
        float wa = exp2f(ma - M), wbv = exp2f(mb - M);
        float inv = 1.0f / (wa * la + wbv * lb);
#pragma unroll
        for (int nd = 0; nd < 8; nd++) {
          float ob = onum[(r0 + rl) * 128 + nd * 16 + fr];
          O[(size_t)(orow + j) * 2048 + h * 128 + nd * 16 + fr] =
              f2bf((wa * oacc[nd][j] + wbv * ob) * inv);
        }
      }
    }
  }
}

extern "C" void kernel_launch(void* const* d_in, const int* in_sizes, int n_in,
                              void* d_out, int out_size, void* d_ws, size_t ws_size,
                              hipStream_t stream) {
  const float* hs = (const float*)d_in[0];
  const float* wq = (const float*)d_in[1];
  const float* wk = (const float*)d_in[2];
  const float* wv = (const float*)d_in[3];
  const float* wo = (const float*)d_in[4];
  char* ws = (char*)d_ws;

  unsigned short* hb   = (unsigned short*)(ws);             // 2048x2048 bf16; later ao
  unsigned short* wqt  = (unsigned short*)(ws + 8388608);   // 2048x2048 bf16
  unsigned short* wkt  = (unsigned short*)(ws + 16777216);  // 512x2048 bf16
  unsigned short* wvt  = (unsigned short*)(ws + 18874368);  // 512x2048 bf16
  unsigned short* wot  = (unsigned short*)(ws + 20971520);  // 2048x2048 bf16
  unsigned short* q_bf = (unsigned short*)(ws + 29360128);  // 2048x2048 bf16
  unsigned short* k_bf = (unsigned short*)(ws + 37748736);  // 2048x512 bf16
  unsigned short* vt_bf= (unsigned short*)(ws + 39845888);  // 512x2048 bf16
  float2* ctab         = (float2*)(ws + 41943040);          // 2048x64 float2 (1 MB)
  unsigned short* ao   = hb;
  float* out = (float*)d_out;

  // fused prep: 10240 transpose blocks + 4096 f2bf blocks + 512 sincos blocks
  k_prep<<<14848, 256, 0, stream>>>(wq, wk, wv, wo, hs, wqt, wkt, wvt, wot, hb, ctab);

  // fused QKV projection: epilogue applies rope -> q_bf/k_bf, V -> vt_bf (transposed)
  k_gemm_bf16<<<dim3(48, 16), 256, 0, stream>>>(hb, wqt, (float*)nullptr,
                                                q_bf, k_bf, vt_bf, ctab,
                                                2048, 3072, 2048, 1);

  // attention: 256 blocks x 512 threads, two q-tiles per block (constant work)
  k_attn_mfma<<<256, 512, 0, stream>>>(q_bf, k_bf, vt_bf, ao);

  // output projection: plain f32 epilogue
  k_gemm_bf16<<<dim3(32, 16), 256, 0, stream>>>(ao, wot, out,
                                                (unsigned short*)nullptr,
                                                (unsigned short*)nullptr,
                                                (unsigned short*)nullptr,
                                                (const float2*)nullptr,
                                                2048, 2048, 2048, 0);
}